// Round 1
// baseline (381.442 us; speedup 1.0000x reference)
//
#include <hip/hip_runtime.h>
#include <hip/hip_bf16.h>
#include <cstdint>

typedef __attribute__((ext_vector_type(8))) short short8_t;
typedef __attribute__((ext_vector_type(4))) short s16x4;
typedef __attribute__((ext_vector_type(4))) float f32x4;

#define SEQ 2048
#define BATCH 2
#define DM 2048
#define NH 16
#define HD 128
#define SCALE 0.08838834764831845f  // 1/sqrt(128)

__device__ __forceinline__ short f2bf(float f) {
    union { __hip_bfloat16 h; short s; } u; u.h = __float2bfloat16(f); return u.s;
}
__device__ __forceinline__ float bf2f(short s) {
    union { short s; __hip_bfloat16 h; } u; u.s = s; return __bfloat162float(u.h);
}

// ---------------- RoPE table ----------------
__global__ void rope_table_kernel(float* __restrict__ cosT, float* __restrict__ sinT) {
    int t = blockIdx.x;      // seq pos
    int i = threadIdx.x;     // 0..63 frequency index
    float inv = exp2f(-(2.0f * (float)i / 128.0f) * log2f(10000.0f));
    float a = (float)t * inv;
    cosT[t * 64 + i] = cosf(a);
    sinT[t * 64 + i] = sinf(a);
}

// ---------------- f32 -> bf16 cast ----------------
__global__ void cast_bf16_kernel(const float* __restrict__ in, short* __restrict__ out, int n4) {
    int i = blockIdx.x * blockDim.x + threadIdx.x;
    int stride = gridDim.x * blockDim.x;
    for (; i < n4; i += stride) {
        float4 v = ((const float4*)in)[i];
        s16x4 o;
        o[0] = f2bf(v.x); o[1] = f2bf(v.y); o[2] = f2bf(v.z); o[3] = f2bf(v.w);
        ((s16x4*)out)[i] = o;
    }
}

// ---------------- L2 norm + scale + cast ----------------
__global__ void __launch_bounds__(256) norm_cast_kernel(const float* __restrict__ x,
                                                        const float* __restrict__ w,
                                                        short* __restrict__ xn) {
    __shared__ float red[4];
    int row = blockIdx.x;                     // (s*2 + b)
    const float* xr = x + (size_t)row * DM;
    short* outr = xn + (size_t)row * DM;
    int t = threadIdx.x;
    float vals[8];
    float ss = 0.f;
#pragma unroll
    for (int i = 0; i < 8; ++i) { float v = xr[t + 256 * i]; vals[i] = v; ss += v * v; }
#pragma unroll
    for (int off = 1; off < 64; off <<= 1) ss += __shfl_xor(ss, off);
    int lane = t & 63, wv = t >> 6;
    if (lane == 0) red[wv] = ss;
    __syncthreads();
    float tot = red[0] + red[1] + red[2] + red[3];
    float inv = 1.f / (sqrtf(tot) + 1e-5f);
#pragma unroll
    for (int i = 0; i < 8; ++i)
        outr[t + 256 * i] = f2bf(vals[i] * inv * w[t + 256 * i]);
}

// ---------------- BT GEMM: C[m][n] = sum_k A[m][k]*B[n][k]  (bf16 in, f32 acc) --------
// MODE 0: QKV -> scatter bf16 to q(b,h,s,d), k(b,h,s,d), v(b,h,d,s), + bias
// MODE 1: f32 out[m*N+n] = acc + bias[n]
template <int MODE>
__global__ void __launch_bounds__(256) gemm_bt(const short* __restrict__ A,
                                               const short* __restrict__ B,
                                               int N, int K,
                                               short* __restrict__ oq, short* __restrict__ ok,
                                               short* __restrict__ ov,
                                               const float* __restrict__ bq,
                                               const float* __restrict__ bk,
                                               const float* __restrict__ bv,
                                               float* __restrict__ outF,
                                               const float* __restrict__ bias) {
    __shared__ short As[128 * 32];
    __shared__ short Bs[128 * 32];
    const int tid = threadIdx.x;
    const int lane = tid & 63;
    const int w = tid >> 6;
    const int wr = w >> 1, wc = w & 1;
    const int brow = blockIdx.y * 128;
    const int bcol = blockIdx.x * 128;

    f32x4 acc[4][4];
#pragma unroll
    for (int i = 0; i < 4; ++i)
#pragma unroll
        for (int j = 0; j < 4; ++j) acc[i][j] = (f32x4){0.f, 0.f, 0.f, 0.f};

    const int l4r = lane >> 2;          // 0..15
    const int l4c = (lane & 3) * 8;     // shorts
    const int fr = lane & 15;
    const int fk = (lane >> 4) * 8;

    for (int kb = 0; kb < K; kb += 32) {
        // stage 8 chunks of 1KB each for A and B; wave w handles chunks w, w+4
#pragma unroll
        for (int c0 = 0; c0 < 2; ++c0) {
            int c = w + c0 * 4;
            int row = c * 16 + l4r;
            const short* ga = A + (size_t)(brow + row) * K + kb + l4c;
            const short* gb = B + (size_t)(bcol + row) * K + kb + l4c;
            __builtin_amdgcn_global_load_lds((const __attribute__((address_space(1))) void*)ga,
                                             (__attribute__((address_space(3))) void*)(As + c * 512),
                                             16, 0, 0);
            __builtin_amdgcn_global_load_lds((const __attribute__((address_space(1))) void*)gb,
                                             (__attribute__((address_space(3))) void*)(Bs + c * 512),
                                             16, 0, 0);
        }
        __syncthreads();
        short8_t af[4], bf[4];
#pragma unroll
        for (int i = 0; i < 4; ++i)
            af[i] = *(const short8_t*)&As[(wr * 64 + i * 16 + fr) * 32 + fk];
#pragma unroll
        for (int j = 0; j < 4; ++j)
            bf[j] = *(const short8_t*)&Bs[(wc * 64 + j * 16 + fr) * 32 + fk];
#pragma unroll
        for (int i = 0; i < 4; ++i)
#pragma unroll
            for (int j = 0; j < 4; ++j)
                acc[i][j] = __builtin_amdgcn_mfma_f32_16x16x32_bf16(af[i], bf[j], acc[i][j], 0, 0, 0);
        __syncthreads();
    }

    // epilogue: C layout col = lane&15, row = (lane>>4)*4 + jj
    const int fq = (lane >> 4) * 4;
#pragma unroll
    for (int i = 0; i < 4; ++i) {
        int mrow = brow + wr * 64 + i * 16 + fq;
#pragma unroll
        for (int j = 0; j < 4; ++j) {
            int ncol = bcol + wc * 64 + j * 16 + fr;
            if (MODE == 0) {
                int which = ncol >> 11;
                int hl = ncol & 2047;
                int h = hl >> 7, d = hl & 127;
                const float* bp = which == 0 ? bq : (which == 1 ? bk : bv);
                short* dst = which == 0 ? oq : (which == 1 ? ok : ov);
                float bval = bp[hl];
#pragma unroll
                for (int jj = 0; jj < 4; ++jj) {
                    int m = mrow + jj;
                    int s = m >> 1, b = m & 1;
                    float v = acc[i][j][jj] + bval;
                    size_t idx;
                    if (which == 2)
                        idx = (((size_t)(b * NH + h)) * HD + d) * SEQ + s;   // V transposed (b,h,d,s)
                    else
                        idx = (((size_t)(b * NH + h)) * SEQ + s) * HD + d;   // (b,h,s,d)
                    dst[idx] = f2bf(v);
                }
            } else {
                float bval = bias[ncol];
#pragma unroll
                for (int jj = 0; jj < 4; ++jj) {
                    int m = mrow + jj;
                    outF[(size_t)m * N + ncol] = acc[i][j][jj] + bval;
                }
            }
        }
    }
}

// ---------------- RoPE in-place on q,k (b,h,s,d) bf16 ----------------
__global__ void __launch_bounds__(256) rope_kernel(short* __restrict__ q, short* __restrict__ k,
                                                   const float* __restrict__ cosT,
                                                   const float* __restrict__ sinT) {
    int w = threadIdx.x >> 6, lane = threadIdx.x & 63;
    int idx = blockIdx.x * 4 + w;            // (b*16+h)*2048 + s
    int s = idx & (SEQ - 1);
    size_t base = (size_t)idx * HD;
    float c = cosT[s * 64 + lane], sn = sinT[s * 64 + lane];
    float q1 = bf2f(q[base + lane]), q2 = bf2f(q[base + lane + 64]);
    q[base + lane] = f2bf(q1 * c - q2 * sn);
    q[base + lane + 64] = f2bf(q2 * c + q1 * sn);
    float k1 = bf2f(k[base + lane]), k2 = bf2f(k[base + lane + 64]);
    k[base + lane] = f2bf(k1 * c - k2 * sn);
    k[base + lane + 64] = f2bf(k2 * c + k1 * sn);
}

// ---------------- Flash attention (causal), 4 waves x 16 q-rows, KV tile 64 ----------
// Q,K in (b,h,s,d); V in (b,h,d,s); AO written as [(s*2+b)][h*128+d] bf16.
__global__ void __launch_bounds__(256) attn_kernel(const short* __restrict__ Q,
                                                   const short* __restrict__ K,
                                                   const short* __restrict__ V,
                                                   short* __restrict__ AO) {
    __shared__ short Kl[64 * 136];       // [kpos][d], padded
    __shared__ short Vt[128 * 88];       // [d][kpos], padded
    __shared__ short Pl[4][16 * 88];     // per-wave P [q][kpos], padded

    const int bh = blockIdx.x;           // b*16+h
    const int qt = blockIdx.y;           // q tile of 64
    const int b = bh >> 4;
    const int h = bh & 15;
    const size_t base = (size_t)bh * (SEQ * HD);
    const int tid = threadIdx.x;
    const int lane = tid & 63;
    const int w = tid >> 6;
    const int fr = lane & 15;
    const int fk = (lane >> 4) * 8;
    const int fq = (lane >> 4) * 4;
    const int qbase = qt * 64 + w * 16;
    const int qg = qbase + fr;           // this lane's q row (S^T layout)

    short8_t qf[4];
#pragma unroll
    for (int kc = 0; kc < 4; ++kc)
        qf[kc] = *(const short8_t*)&Q[base + (size_t)(qbase + fr) * HD + kc * 32 + fk];

    f32x4 acc[8];
#pragma unroll
    for (int dt = 0; dt < 8; ++dt) acc[dt] = (f32x4){0.f, 0.f, 0.f, 0.f};
    float m_r = -1e30f, l_r = 0.f;

    for (int kt = 0; kt <= qt; ++kt) {
        // stage K tile (coalesced b128 -> b128)
#pragma unroll
        for (int p = 0; p < 4; ++p) {
            int idx = p * 256 + tid;
            int r = idx >> 4;
            int c8 = (idx & 15) * 8;
            *(short8_t*)&Kl[r * 136 + c8] =
                *(const short8_t*)&K[base + (size_t)(kt * 64 + r) * HD + c8];
        }
        // stage V^T tile (V already transposed in global: (b,h,d,s))
#pragma unroll
        for (int p = 0; p < 4; ++p) {
            int idx = p * 256 + tid;
            int d = idx >> 3;
            int c8 = (idx & 7) * 8;
            *(short8_t*)&Vt[d * 88 + c8] =
                *(const short8_t*)&V[base + (size_t)d * SEQ + kt * 64 + c8];
        }
        __syncthreads();

        // S^T = K_tile @ Q^T : C col = q (fr), row = kpos (fq+jj within nt)
        f32x4 st[4];
#pragma unroll
        for (int nt = 0; nt < 4; ++nt) {
            f32x4 a = (f32x4){0.f, 0.f, 0.f, 0.f};
#pragma unroll
            for (int kc = 0; kc < 4; ++kc) {
                short8_t kf = *(const short8_t*)&Kl[(nt * 16 + fr) * 136 + kc * 32 + fk];
                a = __builtin_amdgcn_mfma_f32_16x16x32_bf16(kf, qf[kc], a, 0, 0, 0);
            }
            st[nt] = a;
        }

        // causal mask + row max (row = q = fr, replicated over lane groups)
        float rmax = -1e30f;
#pragma unroll
        for (int nt = 0; nt < 4; ++nt) {
#pragma unroll
            for (int jj = 0; jj < 4; ++jj) {
                int kg = kt * 64 + nt * 16 + fq + jj;
                float sv = st[nt][jj];
                sv = (kg > qg) ? -1e30f : sv;
                st[nt][jj] = sv;
                rmax = fmaxf(rmax, sv);
            }
        }
        rmax = fmaxf(rmax, __shfl_xor(rmax, 16));
        rmax = fmaxf(rmax, __shfl_xor(rmax, 32));
        float m_new = fmaxf(m_r, rmax);
        float corr = __expf((m_r - m_new) * SCALE);
        float rsum = 0.f;
#pragma unroll
        for (int nt = 0; nt < 4; ++nt) {
            s16x4 pk;
#pragma unroll
            for (int jj = 0; jj < 4; ++jj) {
                float p = __expf((st[nt][jj] - m_new) * SCALE);
                rsum += p;
                pk[jj] = f2bf(p);
            }
            *(s16x4*)&Pl[w][fr * 88 + nt * 16 + fq] = pk;
        }
        rsum += __shfl_xor(rsum, 16);
        rsum += __shfl_xor(rsum, 32);
        l_r = l_r * corr + rsum;
        m_r = m_new;

        // redistribute corr from q=fr layout to q=fq+jj layout via shuffles
        float c4[4];
#pragma unroll
        for (int jj = 0; jj < 4; ++jj) c4[jj] = __shfl(corr, fq + jj);
#pragma unroll
        for (int dt = 0; dt < 8; ++dt) {
#pragma unroll
            for (int jj = 0; jj < 4; ++jj) acc[dt][jj] *= c4[jj];
        }

        // PV: O[q][d] += P[q][kpos] * V[kpos][d]
#pragma unroll
        for (int kc = 0; kc < 2; ++kc) {
            short8_t pf = *(const short8_t*)&Pl[w][fr * 88 + kc * 32 + fk];
#pragma unroll
            for (int dt = 0; dt < 8; ++dt) {
                short8_t vf = *(const short8_t*)&Vt[(dt * 16 + fr) * 88 + kc * 32 + fk];
                acc[dt] = __builtin_amdgcn_mfma_f32_16x16x32_bf16(pf, vf, acc[dt], 0, 0, 0);
            }
        }
        __syncthreads();
    }

    float linv[4];
#pragma unroll
    for (int jj = 0; jj < 4; ++jj) linv[jj] = 1.f / __shfl(l_r, fq + jj);
#pragma unroll
    for (int dt = 0; dt < 8; ++dt) {
#pragma unroll
        for (int jj = 0; jj < 4; ++jj) {
            int qrow = qbase + fq + jj;
            int d = dt * 16 + fr;
            AO[((size_t)(qrow * BATCH + b)) * DM + h * HD + d] = f2bf(acc[dt][jj] * linv[jj]);
        }
    }
}

extern "C" void kernel_launch(void* const* d_in, const int* in_sizes, int n_in,
                              void* d_out, int out_size, void* d_ws, size_t ws_size,
                              hipStream_t stream) {
    (void)in_sizes; (void)n_in; (void)out_size; (void)ws_size;
    const float* x  = (const float*)d_in[0];
    const float* nw = (const float*)d_in[3];
    const float* qw = (const float*)d_in[4];
    const float* qbias = (const float*)d_in[5];
    const float* kw = (const float*)d_in[6];
    const float* kbias = (const float*)d_in[7];
    const float* vw = (const float*)d_in[8];
    const float* vbias = (const float*)d_in[9];
    const float* ow = (const float*)d_in[10];
    const float* obias = (const float*)d_in[11];
    float* out = (float*)d_out;

    char* ws = (char*)d_ws;
    size_t off = 0;
    float* cosT = (float*)(ws + off); off += (size_t)SEQ * 64 * 4;
    float* sinT = (float*)(ws + off); off += (size_t)SEQ * 64 * 4;
    short* wqkv = (short*)(ws + off); off += (size_t)3 * DM * DM * 2;
    short* wo   = (short*)(ws + off); off += (size_t)DM * DM * 2;
    short* xn   = (short*)(ws + off); off += (size_t)SEQ * BATCH * DM * 2;  // reused as AO
    short* qd   = (short*)(ws + off); off += (size_t)SEQ * BATCH * DM * 2;
    short* kd   = (short*)(ws + off); off += (size_t)SEQ * BATCH * DM * 2;
    short* vd   = (short*)(ws + off); off += (size_t)SEQ * BATCH * DM * 2;
    short* ao   = xn;

    rope_table_kernel<<<SEQ, 64, 0, stream>>>(cosT, sinT);
    cast_bf16_kernel<<<1024, 256, 0, stream>>>(qw, wqkv, DM * DM / 4);
    cast_bf16_kernel<<<1024, 256, 0, stream>>>(kw, wqkv + (size_t)DM * DM, DM * DM / 4);
    cast_bf16_kernel<<<1024, 256, 0, stream>>>(vw, wqkv + (size_t)2 * DM * DM, DM * DM / 4);
    cast_bf16_kernel<<<1024, 256, 0, stream>>>(ow, wo, DM * DM / 4);
    norm_cast_kernel<<<SEQ * BATCH, 256, 0, stream>>>(x, nw, xn);
    gemm_bt<0><<<dim3(3 * DM / 128, SEQ * BATCH / 128), 256, 0, stream>>>(
        xn, wqkv, 3 * DM, DM, qd, kd, vd, qbias, kbias, vbias, nullptr, nullptr);
    rope_kernel<<<BATCH * NH * SEQ / 4, 256, 0, stream>>>(qd, kd, cosT, sinT);
    attn_kernel<<<dim3(BATCH * NH, SEQ / 64), 256, 0, stream>>>(qd, kd, vd, ao);
    gemm_bt<1><<<dim3(DM / 128, SEQ * BATCH / 128), 256, 0, stream>>>(
        ao, wo, DM, DM, nullptr, nullptr, nullptr, nullptr, nullptr, nullptr, out, obias);
}